// Round 8
// baseline (447.569 us; speedup 1.0000x reference)
//
#include <hip/hip_runtime.h>

typedef unsigned int u32;
typedef _Float16 h2v __attribute__((ext_vector_type(2)));
typedef _Float16 h8v __attribute__((ext_vector_type(8)));
typedef float f4v __attribute__((ext_vector_type(4)));

namespace {

constexpr int kB = 256, kT = 1024, kS = 96, kStart = 1;
constexpr float kCF = 3.5f;
constexpr float kLn2 = 0.69314718055994531f;
constexpr int kNT = 16;                    // batch tiles of 16
constexpr int kSlotU = 832;                // u32 per (bt,t) slot: 768 EF + 64 mask
constexpr int kNSlots = kNT * kT;          // 16384
constexpr size_t kEFGu = (size_t)kNSlots * kSlotU;
// f32-unit offsets into ws after the EF table
constexpr size_t OPF  = kEFGu;
constexpr size_t OWB  = OPF + (size_t)kB * kS;
constexpr size_t OLF  = OWB + (size_t)kB * kS;
constexpr size_t OLB  = OLF + kB;
constexpr size_t ONUM = OLB + kB;
constexpr size_t OMS  = ONUM + kB;
constexpr size_t kNeedBytes = (OMS + kB) * 4;

__device__ __forceinline__ u32 pkmul(u32 a, u32 b) {
  u32 d; asm("v_pk_mul_f16 %0, %1, %2" : "=v"(d) : "v"(a), "v"(b)); return d;
}
__device__ __forceinline__ u32 pkmax(u32 a, u32 b) {
  u32 d; asm("v_pk_max_f16 %0, %1, %2" : "=v"(d) : "v"(a), "v"(b)); return d;
}
__device__ __forceinline__ u32 pkrtz(float a, float b) {
  return __builtin_bit_cast(u32, __builtin_amdgcn_cvt_pkrtz(a, b));
}

// ---------------- prep: EF table (fp16, MFMA C-fragment order) + numerator ----------------
__global__ __launch_bounds__(256) void crf_prep(
    const float* __restrict__ F, const int* __restrict__ states,
    const float* __restrict__ mask, const float* __restrict__ trans,
    u32* __restrict__ efg, float* __restrict__ ws) {
  __shared__ float red[256];
  const int blk = blockIdx.x;
  const int tid = threadIdx.x;
  if (blk < kNSlots) {
    const int bt = blk >> 10, t = blk & 1023;
    u32* out = efg + (size_t)blk * kSlotU;
#pragma unroll
    for (int qq = 0; qq < 4; ++qq) {
      const int c = qq * 256 + tid;
      if (c < 768) {
        const int ll = c / 12, j = c % 12;
        const int col = ll & 15, q4 = (ll >> 4) * 4;
        const int s0 = (j >> 1) * 16 + q4 + (j & 1) * 2;
        const int b = bt * 16 + col;
        const float2 fv = *(const float2*)(F + ((size_t)b * kT + t) * kS + s0);
        out[c] = pkrtz(__expf(fv.x - kCF), __expf(fv.y - kCF));
      } else if (c < kSlotU) {
        const int col = (c - 768) & 15;
        out[c] = (mask[(size_t)(bt * 16 + col) * kT + t] > 0.f) ? ~0u : 0u;
      }
    }
    return;
  }
  // numerator + mask-count
  const int b = blk - kNSlots;
  const int* st = states + b * kT;
  const float* Fb = F + (size_t)b * kT * kS;
  const float* mb = mask + b * kT;
  float acc = 0.f, msum = 0.f;
  for (int t = tid; t < kT; t += 256) {
    const int cu = st[t];
    const int pr = (t > 0) ? st[t - 1] : kStart;
    const float mk = mb[t];
    acc += (Fb[(size_t)t * kS + cu] + trans[cu * kS + pr]) * mk;
    msum += mk;
  }
  red[tid] = acc;
  __syncthreads();
  if (tid < 128) red[tid] += red[tid + 128];
  __syncthreads();
  if (tid < 64) {
    float v = red[tid] + red[tid + 64];
#pragma unroll
    for (int off = 32; off > 0; off >>= 1) v += __shfl_xor(v, off, 64);
    if (tid == 0) ws[ONUM + b] = v;
  }
  __syncthreads();
  red[tid] = msum;
  __syncthreads();
  if (tid < 128) red[tid] += red[tid + 128];
  __syncthreads();
  if (tid < 64) {
    float v = red[tid] + red[tid + 64];
#pragma unroll
    for (int off = 32; off > 0; off >>= 1) v += __shfl_xor(v, off, 64);
    if (tid == 0) ws[OMS + b] = v;
  }
}

// ---------------- chains: ONE chain per wave, 32 waves total ----------------
// blocks [0,16) = fwd, [16,32) = bwd. K=32 MFMA with the pi column-permutation
// baked into A (verified R6/R7, absmax=0). New in R8: 3 independent m-partials
// (breaks the dependent-MFMA accumulator chain), renorm scale folded into
// precomputed em/Bsc off the critical path, single chain per wave so the
// serial latency is not issue-coupled with a second chain.

constexpr int RDEPTH = 4;

#define LOADSLOT(EA, MV, T) do {                                              \
    const u32* sp_ = tbase + (size_t)(T) * kSlotU + l * 12;                   \
    EA[0] = ((const uint4*)sp_)[0];                                           \
    EA[1] = ((const uint4*)sp_)[1];                                           \
    EA[2] = ((const uint4*)sp_)[2];                                           \
    MV = tbase[(size_t)(T) * kSlotU + 768 + l];                               \
  } while (0)

#define STALESC()                                                             \
    u32 m_ = B[0][0];                                                         \
    _Pragma("unroll") for (int kt_ = 0; kt_ < 6; ++kt_)                       \
      _Pragma("unroll") for (int pr_ = 0; pr_ < 2; ++pr_)                     \
        if (kt_ | pr_) m_ = pkmax(m_, B[kt_][pr_]);                           \
    m_ = pkmax(m_, (u32)__shfl_xor((int)m_, 16, 64));                         \
    m_ = pkmax(m_, (u32)__shfl_xor((int)m_, 32, 64));                         \
    m_ = pkmax(m_, (m_ >> 16) | (m_ << 16));                                  \
    int e_ = (int)((m_ >> 10) & 31);                                          \
    e_ = e_ < 1 ? 1 : (e_ > 29 ? 29 : e_);                                    \
    Lacc += (float)(e_ - 15) * kLn2;                                          \
    u32 sc_ = ((u32)(30 - e_) << 10);                                         \
    sc_ |= sc_ << 16

#define MFMA18()                                                              \
    f4v P0[6], P1[6], P2[6];                                                  \
    _Pragma("unroll") for (int it = 0; it < 6; ++it) {                        \
      P0[it] = __builtin_amdgcn_mfma_f32_16x16x32_f16(Am[it][0], bk_[0], z4, 0, 0, 0); \
      P1[it] = __builtin_amdgcn_mfma_f32_16x16x32_f16(Am[it][1], bk_[1], z4, 0, 0, 0); \
      P2[it] = __builtin_amdgcn_mfma_f32_16x16x32_f16(Am[it][2], bk_[2], z4, 0, 0, 0); \
    }

// fwd step: B' = cnd(mask, pkrtz(M·B) * (ef*sc), B*sc)
#define FSTEP(K, S) do {                                                      \
    STALESC();                                                                \
    const u32* efp_ = (const u32*)eR[K];                                      \
    u32 em_[12], Bsc_[12];                                                    \
    _Pragma("unroll") for (int j = 0; j < 12; ++j) {                          \
      em_[j] = pkmul(efp_[j], sc_);                                           \
      Bsc_[j] = pkmul(B[j >> 1][j & 1], sc_);                                 \
    }                                                                         \
    const u32 mw_ = mR[K];                                                    \
    h8v bk_[3];                                                               \
    _Pragma("unroll") for (int m = 0; m < 3; ++m) {                           \
      uint4 t_{B[2 * m][0], B[2 * m][1], B[2 * m + 1][0], B[2 * m + 1][1]};   \
      bk_[m] = __builtin_bit_cast(h8v, t_);                                   \
    }                                                                         \
    { int t_ = (S) + RDEPTH; if (t_ > 511) t_ = 511;                          \
      LOADSLOT(eR[K], mR[K], t_); }                                           \
    MFMA18();                                                                 \
    _Pragma("unroll") for (int it = 0; it < 6; ++it) {                        \
      const f4v C_ = (P0[it] + P1[it]) + P2[it];                              \
      _Pragma("unroll") for (int pr = 0; pr < 2; ++pr) {                      \
        const u32 nv_ = pkmul(pkrtz(C_[2 * pr], C_[2 * pr + 1]), em_[it * 2 + pr]); \
        B[it][pr] = mw_ ? nv_ : Bsc_[it * 2 + pr];                            \
      }                                                                       \
    }                                                                         \
  } while (0)

// bwd step: B' = cnd(mask, pkrtz(M^T·(B*ef)), B) * sc
#define BSTEP(K, S) do {                                                      \
    STALESC();                                                                \
    const u32* efp_ = (const u32*)eR[K];                                      \
    const u32 mw_ = mR[K];                                                    \
    u32 Bu_[12];                                                              \
    _Pragma("unroll") for (int j = 0; j < 12; ++j)                            \
      Bu_[j] = pkmul(B[j >> 1][j & 1], efp_[j]);                              \
    h8v bk_[3];                                                               \
    _Pragma("unroll") for (int m = 0; m < 3; ++m) {                           \
      uint4 t_{Bu_[4 * m], Bu_[4 * m + 1], Bu_[4 * m + 2], Bu_[4 * m + 3]};   \
      bk_[m] = __builtin_bit_cast(h8v, t_);                                   \
    }                                                                         \
    { int t_ = 1023 - ((S) + RDEPTH); if (t_ < 512) t_ = 512;                 \
      LOADSLOT(eR[K], mR[K], t_); }                                           \
    MFMA18();                                                                 \
    _Pragma("unroll") for (int it = 0; it < 6; ++it) {                        \
      const f4v C_ = (P0[it] + P1[it]) + P2[it];                              \
      _Pragma("unroll") for (int pr = 0; pr < 2; ++pr) {                      \
        u32 nv_ = pkrtz(C_[2 * pr], C_[2 * pr + 1]);                          \
        nv_ = mw_ ? nv_ : B[it][pr];                                          \
        B[it][pr] = pkmul(nv_, sc_);                                          \
      }                                                                       \
    }                                                                         \
  } while (0)

__global__ __launch_bounds__(64, 1) void crf_chains3(
    const u32* __restrict__ efg, const float* __restrict__ trans,
    float* __restrict__ ws) {
  const int bid = blockIdx.x;
  const bool bwd = bid >= kNT;
  const int bt = bwd ? bid - kNT : bid;
  const int l = threadIdx.x;
  const int q_ = l >> 4, r = l & 15;
  const u32* tbase = efg + (size_t)bt * kT * kSlotU;

  // A matrix in fragment layout with the pi column-permutation baked in.
  h8v Am[6][3];
#pragma unroll
  for (int it = 0; it < 6; ++it)
#pragma unroll
    for (int m = 0; m < 3; ++m) {
      u32 w[4];
#pragma unroll
      for (int jj = 0; jj < 4; ++jj) {
        const int p0 = 32 * m + 16 * (jj >> 1) + 4 * q_ + 2 * (jj & 1);
        const int rowi = 16 * it + r;
        if (!bwd)
          w[jj] = pkrtz(__expf(trans[rowi * kS + p0] - kCF),
                        __expf(trans[rowi * kS + p0 + 1] - kCF));
        else
          w[jj] = pkrtz(__expf(trans[p0 * kS + rowi] - kCF),
                        __expf(trans[(p0 + 1) * kS + rowi] - kCF));
      }
      uint4 u4{w[0], w[1], w[2], w[3]};
      Am[it][m] = __builtin_bit_cast(h8v, u4);
    }

  u32 B[6][2];
#pragma unroll
  for (int kt = 0; kt < 6; ++kt)
#pragma unroll
    for (int pr = 0; pr < 2; ++pr)
      B[kt][pr] = bwd ? 0x3C003C00u : 0u;
  if (!bwd && q_ == 0) B[0][0] = 0x3C000000u;  // p0 = e_{state 1}

  float Lacc = 0.f;
  const f4v z4 = {0.f, 0.f, 0.f, 0.f};

  uint4 eR[RDEPTH][3];
  u32 mR[RDEPTH];
#pragma unroll
  for (int k = 0; k < RDEPTH; ++k) {
    const int t = bwd ? (1023 - k) : k;
    LOADSLOT(eR[k], mR[k], t);
  }

  if (!bwd) {
    for (int s = 0; s < 512; s += 4) {
      FSTEP(0, s);
      FSTEP(1, s + 1);
      FSTEP(2, s + 2);
      FSTEP(3, s + 3);
    }
  } else {
    for (int s = 0; s < 512; s += 4) {
      BSTEP(0, s);
      BSTEP(1, s + 1);
      BSTEP(2, s + 2);
      BSTEP(3, s + 3);
    }
  }

  float* dst = ws + (bwd ? OWB : OPF) + ((size_t)bt * 16 + r) * kS;
#pragma unroll
  for (int kt = 0; kt < 6; ++kt)
#pragma unroll
    for (int pr = 0; pr < 2; ++pr) {
      const int s0 = kt * 16 + q_ * 4 + pr * 2;
      const h2v hv = __builtin_bit_cast(h2v, B[kt][pr]);
      dst[s0] = (float)hv[0];
      dst[s0 + 1] = (float)hv[1];
    }
  if (l < 16) ws[(bwd ? OLB : OLF) + bt * 16 + l] = Lacc;
}

// ---------------- finalize ----------------
__global__ __launch_bounds__(64) void crf_fin(
    const float* __restrict__ ws, float* __restrict__ out) {
  const int b = blockIdx.x, l = threadIdx.x;
  float d = ws[OPF + (size_t)b * kS + l] * ws[OWB + (size_t)b * kS + l];
  if (l < 32) d += ws[OPF + (size_t)b * kS + 64 + l] * ws[OWB + (size_t)b * kS + 64 + l];
#pragma unroll
  for (int off = 32; off; off >>= 1) d += __shfl_xor(d, off, 64);
  if (l == 0)
    out[b] = (ws[OLF + b] + ws[OLB + b] + logf(d) + 2.f * kCF * ws[OMS + b]) - ws[ONUM + b];
}

// ================= fallback path (R3, known-good) if ws is too small =================
constexpr int FB_PF = 0;
constexpr int FB_LF = kB * kS;
constexpr int FB_WB = FB_LF + kB;
constexpr int FB_LB = FB_WB + kB * kS;

__device__ __forceinline__ void renorm96(const float4* pv, float& pnew, float& Lacc) {
  float4 m4 = pv[0];
#pragma unroll
  for (int k = 1; k < 12; ++k) {
    m4.x = fmaxf(m4.x, pv[k].x); m4.y = fmaxf(m4.y, pv[k].y);
    m4.z = fmaxf(m4.z, pv[k].z); m4.w = fmaxf(m4.w, pv[k].w);
  }
  float m = fmaxf(fmaxf(m4.x, m4.y), fmaxf(m4.z, m4.w));
  m = fmaxf(m, __shfl_xor(m, 1, 64));
  const int e = (__float_as_int(m) >> 23) & 0xFF;
  const float scale = __int_as_float((254 - e) << 23);
  Lacc += (float)(e - 127) * kLn2;
  pnew *= scale;
}

__global__ __launch_bounds__(192) void fb_halves(
    const float* __restrict__ F, const float* __restrict__ mask,
    const float* __restrict__ trans, float* __restrict__ ws) {
  const bool bwd = blockIdx.x >= kB;
  const int b = bwd ? (blockIdx.x - kB) : blockIdx.x;
  const int tid = threadIdx.x;
  const int h = tid & 1;
  const int i = tid >> 1;
  __shared__ __align__(16) float pbuf[2][kS];
  __shared__ __align__(16) float fl[2][16 * kS];
  __shared__ __align__(16) float ml[kT];
  const float* Fb = F + (size_t)b * kT * kS;
  float mwv[48];
  if (!bwd) {
    const float4* tp = (const float4*)(trans + i * kS + h * 48);
#pragma unroll
    for (int k = 0; k < 12; ++k) {
      const float4 tv = tp[k];
      mwv[4 * k + 0] = __expf(tv.x - kCF); mwv[4 * k + 1] = __expf(tv.y - kCF);
      mwv[4 * k + 2] = __expf(tv.z - kCF); mwv[4 * k + 3] = __expf(tv.w - kCF);
    }
  } else {
#pragma unroll
    for (int k = 0; k < 48; ++k) mwv[k] = __expf(trans[(h * 48 + k) * kS + i] - kCF);
  }
  const int gb0 = bwd ? (kT - 16) : 0;
  const int gstep = bwd ? -16 : 16;
  {
    const float4* s = (const float4*)(Fb + (size_t)gb0 * kS + tid * 8);
    const float4 a = s[0], c4 = s[1];
    *(float4*)&fl[0][tid * 8] = a;
    *(float4*)&fl[0][tid * 8 + 4] = c4;
    const float4* mb4 = (const float4*)(mask + (size_t)b * kT);
    for (int idx = tid; idx < kT / 4; idx += 192) ((float4*)ml)[idx] = mb4[idx];
    if (!bwd && h == 0) pbuf[0][i] = (i == kStart) ? 1.0f : 0.0f;
  }
  __syncthreads();
  float Lacc = 0.0f;
  float pown = bwd ? 1.0f : ((i == kStart) ? 1.0f : 0.0f);
  int cur = 0;
  float4 pfa, pfb;
  for (int tc = 0; tc < 32; ++tc) {
    const int fbuf = tc & 1;
    if (tc < 31) {
      const float4* s = (const float4*)(Fb + (size_t)(gb0 + (tc + 1) * gstep) * kS + tid * 8);
      pfa = s[0]; pfb = s[1];
    }
#pragma unroll
    for (int tt = 0; tt < 16; ++tt) {
      const int tl = tc * 16 + tt;
      const int t = bwd ? (kT - 1 - tl) : tl;
      const float f = fl[fbuf][(bwd ? (15 - tt) : tt) * kS + i];
      const float mkv = ml[t];
      if (!bwd) {
        const float* pc = &pbuf[cur][h * 48];
        float4 pv[12];
#pragma unroll
        for (int k = 0; k < 12; ++k) pv[k] = ((const float4*)pc)[k];
        float a0 = 0.f, a1 = 0.f, a2 = 0.f, a3 = 0.f;
#pragma unroll
        for (int k = 0; k < 12; ++k) {
          a0 = fmaf(mwv[4 * k + 0], pv[k].x, a0); a1 = fmaf(mwv[4 * k + 1], pv[k].y, a1);
          a2 = fmaf(mwv[4 * k + 2], pv[k].z, a2); a3 = fmaf(mwv[4 * k + 3], pv[k].w, a3);
        }
        float acc = (a0 + a1) + (a2 + a3);
        acc += __shfl_xor(acc, 1, 64);
        float pnew = (mkv > 0.f) ? acc * __expf(f - kCF) : pown;
        if (((tt + 1) & 7) == 0) renorm96(pv, pnew, Lacc);
        if (tt == 15 && tc < 31) {
          *(float4*)&fl[fbuf ^ 1][tid * 8] = pfa;
          *(float4*)&fl[fbuf ^ 1][tid * 8 + 4] = pfb;
        }
        if (h == 0) pbuf[cur ^ 1][i] = pnew;
        __syncthreads();
        pown = pnew;
      } else {
        const float uu = pown * __expf(f - kCF);
        if (h == 0) pbuf[cur ^ 1][i] = uu;
        if (tt == 15 && tc < 31) {
          *(float4*)&fl[fbuf ^ 1][tid * 8] = pfa;
          *(float4*)&fl[fbuf ^ 1][tid * 8 + 4] = pfb;
        }
        __syncthreads();
        const float* pc = &pbuf[cur ^ 1][h * 48];
        float4 pv[12];
#pragma unroll
        for (int k = 0; k < 12; ++k) pv[k] = ((const float4*)pc)[k];
        float a0 = 0.f, a1 = 0.f, a2 = 0.f, a3 = 0.f;
#pragma unroll
        for (int k = 0; k < 12; ++k) {
          a0 = fmaf(mwv[4 * k + 0], pv[k].x, a0); a1 = fmaf(mwv[4 * k + 1], pv[k].y, a1);
          a2 = fmaf(mwv[4 * k + 2], pv[k].z, a2); a3 = fmaf(mwv[4 * k + 3], pv[k].w, a3);
        }
        float acc = (a0 + a1) + (a2 + a3);
        acc += __shfl_xor(acc, 1, 64);
        float pnew = (mkv > 0.f) ? acc : pown;
        if (((tt + 1) & 7) == 0) renorm96(pv, pnew, Lacc);
        pown = pnew;
      }
      cur ^= 1;
    }
  }
  if (h == 0) ws[(bwd ? FB_WB : FB_PF) + b * kS + i] = pown;
  if (tid == 0) ws[(bwd ? FB_LB : FB_LF) + b] = Lacc;
}

__global__ __launch_bounds__(256) void fb_finalize(
    const float* __restrict__ F, const int* __restrict__ states,
    const float* __restrict__ mask, const float* __restrict__ trans,
    const float* __restrict__ ws, float* __restrict__ out) {
  const int b = blockIdx.x;
  const int tid = threadIdx.x;
  const int* st = states + b * kT;
  const float* Fb = F + (size_t)b * kT * kS;
  const float* mb = mask + b * kT;
  float acc = 0.f;
  for (int t = tid; t < kT; t += 256) {
    const int cu = st[t];
    const int pr = (t > 0) ? st[t - 1] : kStart;
    acc += (Fb[(size_t)t * kS + cu] + trans[cu * kS + pr]) * mb[t];
  }
  __shared__ float red[256];
  red[tid] = acc;
  __syncthreads();
  if (tid < 128) red[tid] += red[tid + 128];
  __syncthreads();
  float numv = 0.f;
  if (tid < 64) {
    float v = red[tid] + red[tid + 64];
#pragma unroll
    for (int off = 32; off > 0; off >>= 1) v += __shfl_xor(v, off, 64);
    numv = v;
  }
  __syncthreads();
  float dv = 0.f;
  if (tid < kS) dv = ws[FB_PF + b * kS + tid] * ws[FB_WB + b * kS + tid];
  red[tid] = dv;
  __syncthreads();
  if (tid < 128) red[tid] += red[tid + 128];
  __syncthreads();
  if (tid < 64) {
    float v = red[tid] + red[tid + 64];
#pragma unroll
    for (int off = 32; off > 0; off >>= 1) v += __shfl_xor(v, off, 64);
    if (tid == 0) out[b] = (ws[FB_LF + b] + ws[FB_LB + b] + logf(v)) - numv;
  }
}

}  // namespace

extern "C" void kernel_launch(void* const* d_in, const int* in_sizes, int n_in,
                              void* d_out, int out_size, void* d_ws, size_t ws_size,
                              hipStream_t stream) {
  const float* F      = (const float*)d_in[0];
  const int*   states = (const int*)d_in[1];
  const float* mask   = (const float*)d_in[2];
  const float* trans  = (const float*)d_in[3];
  float* out = (float*)d_out;
  if (ws_size >= kNeedBytes) {
    hipLaunchKernelGGL(crf_prep, dim3(kNSlots + kB), dim3(256), 0, stream,
                       F, states, mask, trans, (u32*)d_ws, (float*)d_ws);
    hipLaunchKernelGGL(crf_chains3, dim3(2 * kNT), dim3(64), 0, stream,
                       (const u32*)d_ws, trans, (float*)d_ws);
    hipLaunchKernelGGL(crf_fin, dim3(kB), dim3(64), 0, stream,
                       (const float*)d_ws, out);
  } else {
    float* ws = (float*)d_ws;
    hipLaunchKernelGGL(fb_halves, dim3(2 * kB), dim3(192), 0, stream, F, mask, trans, ws);
    hipLaunchKernelGGL(fb_finalize, dim3(kB), dim3(256), 0, stream,
                       F, states, mask, trans, ws, out);
  }
}

// Round 9
// 433.169 us; speedup vs baseline: 1.0332x; 1.0332x over previous
//
#include <hip/hip_runtime.h>

typedef unsigned int u32;
typedef _Float16 h2v __attribute__((ext_vector_type(2)));
typedef _Float16 h8v __attribute__((ext_vector_type(8)));
typedef float f4v __attribute__((ext_vector_type(4)));

namespace {

constexpr int kB = 256, kT = 1024, kS = 96, kStart = 1;
constexpr float kCF = 3.5f;          // fallback path only
constexpr float kCM = 3.0625f;       // transition centering
constexpr float kCE = 0.5f;          // emission centering
constexpr float kCT = kCM + kCE;     // total per-unmasked-step log deficit
constexpr float kLn2 = 0.69314718055994531f;
constexpr int kNT = 16;                    // batch tiles of 16
constexpr int kSlotU = 832;                // u32 per (bt,t) slot: 768 EF + 64 mask
constexpr int kNSlots = kNT * kT;          // 16384
constexpr size_t kEFGu = (size_t)kNSlots * kSlotU;
// f32-unit offsets into ws after the EF table
constexpr size_t OPF  = kEFGu;
constexpr size_t OWB  = OPF + (size_t)kB * kS;
constexpr size_t OLF  = OWB + (size_t)kB * kS;
constexpr size_t OLB  = OLF + kB;
constexpr size_t ONUM = OLB + kB;
constexpr size_t OMS  = ONUM + kB;
constexpr size_t kNeedBytes = (OMS + kB) * 4;

__device__ __forceinline__ u32 pkmul(u32 a, u32 b) {
  u32 d; asm("v_pk_mul_f16 %0, %1, %2" : "=v"(d) : "v"(a), "v"(b)); return d;
}
__device__ __forceinline__ u32 pkmax(u32 a, u32 b) {
  u32 d; asm("v_pk_max_f16 %0, %1, %2" : "=v"(d) : "v"(a), "v"(b)); return d;
}
__device__ __forceinline__ u32 pkrtz(float a, float b) {
  return __builtin_bit_cast(u32, __builtin_amdgcn_cvt_pkrtz(a, b));
}

// ---------------- prep: EF table (fp16, MFMA C-fragment order) + numerator ----------------
__global__ __launch_bounds__(256) void crf_prep(
    const float* __restrict__ F, const int* __restrict__ states,
    const float* __restrict__ mask, const float* __restrict__ trans,
    u32* __restrict__ efg, float* __restrict__ ws) {
  __shared__ float red[256];
  const int blk = blockIdx.x;
  const int tid = threadIdx.x;
  if (blk < kNSlots) {
    const int bt = blk >> 10, t = blk & 1023;
    u32* out = efg + (size_t)blk * kSlotU;
#pragma unroll
    for (int qq = 0; qq < 4; ++qq) {
      const int c = qq * 256 + tid;
      if (c < 768) {
        const int ll = c / 12, j = c % 12;
        const int col = ll & 15, q4 = (ll >> 4) * 4;
        const int s0 = (j >> 1) * 16 + q4 + (j & 1) * 2;
        const int b = bt * 16 + col;
        const float2 fv = *(const float2*)(F + ((size_t)b * kT + t) * kS + s0);
        out[c] = pkrtz(__expf(fv.x - kCE), __expf(fv.y - kCE));
      } else if (c < kSlotU) {
        const int col = (c - 768) & 15;
        out[c] = (mask[(size_t)(bt * 16 + col) * kT + t] > 0.f) ? ~0u : 0u;
      }
    }
    return;
  }
  // numerator + mask-count
  const int b = blk - kNSlots;
  const int* st = states + b * kT;
  const float* Fb = F + (size_t)b * kT * kS;
  const float* mb = mask + b * kT;
  float acc = 0.f, msum = 0.f;
  for (int t = tid; t < kT; t += 256) {
    const int cu = st[t];
    const int pr = (t > 0) ? st[t - 1] : kStart;
    const float mk = mb[t];
    acc += (Fb[(size_t)t * kS + cu] + trans[cu * kS + pr]) * mk;
    msum += mk;
  }
  red[tid] = acc;
  __syncthreads();
  if (tid < 128) red[tid] += red[tid + 128];
  __syncthreads();
  if (tid < 64) {
    float v = red[tid] + red[tid + 64];
#pragma unroll
    for (int off = 32; off > 0; off >>= 1) v += __shfl_xor(v, off, 64);
    if (tid == 0) ws[ONUM + b] = v;
  }
  __syncthreads();
  red[tid] = msum;
  __syncthreads();
  if (tid < 128) red[tid] += red[tid + 128];
  __syncthreads();
  if (tid < 64) {
    float v = red[tid] + red[tid + 64];
#pragma unroll
    for (int off = 32; off > 0; off >>= 1) v += __shfl_xor(v, off, 64);
    if (tid == 0) ws[OMS + b] = v;
  }
}

// ---------------- chains: 4 blocks x 8 waves; 2 waves per SIMD ----------------
// Each wave owns ONE chain (tile bt, direction). K=32 MFMA with the pi
// column-permutation baked into A (verified R6-R8, absmax<=2048). Recentered
// constants (kCM+kCE ~= logsumexp growth) make per-step growth ~e^0, so renorm
// (stale, off-path) runs every 4th step only. Hardware wave interleave (2
// waves/SIMD) hides each chain's exposed latency with the sibling's work.

constexpr int RD = 4;   // prefetch ring depth (slots)

#define LOADSLOT(EA, MV, T) do {                                              \
    const u32* sp_ = tbase + (size_t)(T) * kSlotU + l * 12;                   \
    EA[0] = ((const uint4*)sp_)[0];                                           \
    EA[1] = ((const uint4*)sp_)[1];                                           \
    EA[2] = ((const uint4*)sp_)[2];                                           \
    MV = tbase[(size_t)(T) * kSlotU + 768 + l];                               \
  } while (0)

#define STALESC()                                                             \
    u32 m_ = B[0][0];                                                         \
    _Pragma("unroll") for (int kt_ = 0; kt_ < 6; ++kt_)                       \
      _Pragma("unroll") for (int pr_ = 0; pr_ < 2; ++pr_)                     \
        if (kt_ | pr_) m_ = pkmax(m_, B[kt_][pr_]);                           \
    m_ = pkmax(m_, (u32)__shfl_xor((int)m_, 16, 64));                         \
    m_ = pkmax(m_, (u32)__shfl_xor((int)m_, 32, 64));                         \
    m_ = pkmax(m_, (m_ >> 16) | (m_ << 16));                                  \
    int e_ = (int)((m_ >> 10) & 31);                                          \
    e_ = e_ < 1 ? 1 : (e_ > 29 ? 29 : e_);                                    \
    Lacc += (float)(e_ - 15) * kLn2;                                          \
    u32 sc_ = ((u32)(30 - e_) << 10);                                         \
    sc_ |= sc_ << 16

// One chain step. BWD/RN are literal 0/1 -> folded at compile time.
#define STEP(K, S, BWD, RN) do {                                              \
    const u32* efp_ = (const u32*)eR[K];                                      \
    const u32 mw_ = mR[K];                                                    \
    h8v bk_[3];                                                               \
    if (BWD) {                                                                \
      u32 Bu_[12];                                                            \
      _Pragma("unroll") for (int j = 0; j < 12; ++j)                          \
        Bu_[j] = pkmul(B[j >> 1][j & 1], efp_[j]);                            \
      _Pragma("unroll") for (int m = 0; m < 3; ++m) {                         \
        uint4 t_{Bu_[4 * m], Bu_[4 * m + 1], Bu_[4 * m + 2], Bu_[4 * m + 3]}; \
        bk_[m] = __builtin_bit_cast(h8v, t_);                                 \
      }                                                                       \
    } else {                                                                  \
      _Pragma("unroll") for (int m = 0; m < 3; ++m) {                         \
        uint4 t_{B[2 * m][0], B[2 * m][1], B[2 * m + 1][0], B[2 * m + 1][1]}; \
        bk_[m] = __builtin_bit_cast(h8v, t_);                                 \
      }                                                                       \
    }                                                                         \
    { int t_;                                                                 \
      if (BWD) { t_ = 1023 - ((S) + RD); if (t_ < 512) t_ = 512; }            \
      else     { t_ = (S) + RD; if (t_ > 511) t_ = 511; }                     \
      LOADSLOT(eR[K], mR[K], t_); }                                           \
    f4v P0_[6], P1_[6];                                                       \
    _Pragma("unroll") for (int it = 0; it < 6; ++it) {                        \
      P0_[it] = __builtin_amdgcn_mfma_f32_16x16x32_f16(Am[it][0], bk_[0], z4, 0, 0, 0); \
      P1_[it] = __builtin_amdgcn_mfma_f32_16x16x32_f16(Am[it][2], bk_[2], z4, 0, 0, 0); \
    }                                                                         \
    _Pragma("unroll") for (int it = 0; it < 6; ++it)                          \
      P0_[it] = __builtin_amdgcn_mfma_f32_16x16x32_f16(Am[it][1], bk_[1], P0_[it], 0, 0, 0); \
    _Pragma("unroll") for (int it = 0; it < 6; ++it) {                        \
      const f4v C_ = P0_[it] + P1_[it];                                       \
      _Pragma("unroll") for (int pr = 0; pr < 2; ++pr) {                      \
        u32 nv_ = pkrtz(C_[2 * pr], C_[2 * pr + 1]);                          \
        if (!(BWD)) nv_ = pkmul(nv_, efp_[it * 2 + pr]);                      \
        B[it][pr] = mw_ ? nv_ : B[it][pr];                                    \
      }                                                                       \
    }                                                                         \
    if (RN) {                                                                 \
      STALESC();                                                              \
      _Pragma("unroll") for (int j = 0; j < 12; ++j)                          \
        B[j >> 1][j & 1] = pkmul(B[j >> 1][j & 1], sc_);                      \
    }                                                                         \
  } while (0)

__global__ __launch_bounds__(512, 2) void crf_chains4(
    const u32* __restrict__ efg, const float* __restrict__ trans,
    float* __restrict__ ws) {
  const int wid = threadIdx.x >> 6;
  const int l = threadIdx.x & 63;
  const int bt = blockIdx.x * 4 + (wid >> 1);
  const bool bwd = wid & 1;
  const int q_ = l >> 4, r = l & 15;
  const u32* tbase = efg + (size_t)bt * kT * kSlotU;

  // A matrix in fragment layout with the pi column-permutation baked in.
  h8v Am[6][3];
#pragma unroll
  for (int it = 0; it < 6; ++it)
#pragma unroll
    for (int m = 0; m < 3; ++m) {
      u32 w[4];
#pragma unroll
      for (int jj = 0; jj < 4; ++jj) {
        const int p0 = 32 * m + 16 * (jj >> 1) + 4 * q_ + 2 * (jj & 1);
        const int rowi = 16 * it + r;
        if (!bwd)
          w[jj] = pkrtz(__expf(trans[rowi * kS + p0] - kCM),
                        __expf(trans[rowi * kS + p0 + 1] - kCM));
        else
          w[jj] = pkrtz(__expf(trans[p0 * kS + rowi] - kCM),
                        __expf(trans[(p0 + 1) * kS + rowi] - kCM));
      }
      uint4 u4{w[0], w[1], w[2], w[3]};
      Am[it][m] = __builtin_bit_cast(h8v, u4);
    }

  u32 B[6][2];
#pragma unroll
  for (int kt = 0; kt < 6; ++kt)
#pragma unroll
    for (int pr = 0; pr < 2; ++pr)
      B[kt][pr] = bwd ? 0x3C003C00u : 0u;
  if (!bwd && q_ == 0) B[0][0] = 0x3C000000u;  // p0 = e_{state 1}

  float Lacc = 0.f;
  const f4v z4 = {0.f, 0.f, 0.f, 0.f};

  uint4 eR[RD][3];
  u32 mR[RD];
#pragma unroll
  for (int k = 0; k < RD; ++k) {
    const int t = bwd ? (1023 - k) : k;
    LOADSLOT(eR[k], mR[k], t);
  }

  if (!bwd) {
    for (int s = 0; s < 512; s += 8) {
      STEP(0, s,     0, 0); STEP(1, s + 1, 0, 0);
      STEP(2, s + 2, 0, 0); STEP(3, s + 3, 0, 1);
      STEP(0, s + 4, 0, 0); STEP(1, s + 5, 0, 0);
      STEP(2, s + 6, 0, 0); STEP(3, s + 7, 0, 1);
    }
  } else {
    for (int s = 0; s < 512; s += 8) {
      STEP(0, s,     1, 0); STEP(1, s + 1, 1, 0);
      STEP(2, s + 2, 1, 0); STEP(3, s + 3, 1, 1);
      STEP(0, s + 4, 1, 0); STEP(1, s + 5, 1, 0);
      STEP(2, s + 6, 1, 0); STEP(3, s + 7, 1, 1);
    }
  }

  float* dst = ws + (bwd ? OWB : OPF) + ((size_t)bt * 16 + r) * kS;
#pragma unroll
  for (int kt = 0; kt < 6; ++kt)
#pragma unroll
    for (int pr = 0; pr < 2; ++pr) {
      const int s0 = kt * 16 + q_ * 4 + pr * 2;
      const h2v hv = __builtin_bit_cast(h2v, B[kt][pr]);
      dst[s0] = (float)hv[0];
      dst[s0 + 1] = (float)hv[1];
    }
  if (l < 16) ws[(bwd ? OLB : OLF) + bt * 16 + l] = Lacc;
}

// ---------------- finalize ----------------
__global__ __launch_bounds__(64) void crf_fin(
    const float* __restrict__ ws, float* __restrict__ out) {
  const int b = blockIdx.x, l = threadIdx.x;
  float d = ws[OPF + (size_t)b * kS + l] * ws[OWB + (size_t)b * kS + l];
  if (l < 32) d += ws[OPF + (size_t)b * kS + 64 + l] * ws[OWB + (size_t)b * kS + 64 + l];
#pragma unroll
  for (int off = 32; off; off >>= 1) d += __shfl_xor(d, off, 64);
  if (l == 0)
    out[b] = (ws[OLF + b] + ws[OLB + b] + logf(d) + kCT * ws[OMS + b]) - ws[ONUM + b];
}

// ================= fallback path (R3, known-good) if ws is too small =================
constexpr int FB_PF = 0;
constexpr int FB_LF = kB * kS;
constexpr int FB_WB = FB_LF + kB;
constexpr int FB_LB = FB_WB + kB * kS;

__device__ __forceinline__ void renorm96(const float4* pv, float& pnew, float& Lacc) {
  float4 m4 = pv[0];
#pragma unroll
  for (int k = 1; k < 12; ++k) {
    m4.x = fmaxf(m4.x, pv[k].x); m4.y = fmaxf(m4.y, pv[k].y);
    m4.z = fmaxf(m4.z, pv[k].z); m4.w = fmaxf(m4.w, pv[k].w);
  }
  float m = fmaxf(fmaxf(m4.x, m4.y), fmaxf(m4.z, m4.w));
  m = fmaxf(m, __shfl_xor(m, 1, 64));
  const int e = (__float_as_int(m) >> 23) & 0xFF;
  const float scale = __int_as_float((254 - e) << 23);
  Lacc += (float)(e - 127) * kLn2;
  pnew *= scale;
}

__global__ __launch_bounds__(192) void fb_halves(
    const float* __restrict__ F, const float* __restrict__ mask,
    const float* __restrict__ trans, float* __restrict__ ws) {
  const bool bwd = blockIdx.x >= kB;
  const int b = bwd ? (blockIdx.x - kB) : blockIdx.x;
  const int tid = threadIdx.x;
  const int h = tid & 1;
  const int i = tid >> 1;
  __shared__ __align__(16) float pbuf[2][kS];
  __shared__ __align__(16) float fl[2][16 * kS];
  __shared__ __align__(16) float ml[kT];
  const float* Fb = F + (size_t)b * kT * kS;
  float mwv[48];
  if (!bwd) {
    const float4* tp = (const float4*)(trans + i * kS + h * 48);
#pragma unroll
    for (int k = 0; k < 12; ++k) {
      const float4 tv = tp[k];
      mwv[4 * k + 0] = __expf(tv.x - kCF); mwv[4 * k + 1] = __expf(tv.y - kCF);
      mwv[4 * k + 2] = __expf(tv.z - kCF); mwv[4 * k + 3] = __expf(tv.w - kCF);
    }
  } else {
#pragma unroll
    for (int k = 0; k < 48; ++k) mwv[k] = __expf(trans[(h * 48 + k) * kS + i] - kCF);
  }
  const int gb0 = bwd ? (kT - 16) : 0;
  const int gstep = bwd ? -16 : 16;
  {
    const float4* s = (const float4*)(Fb + (size_t)gb0 * kS + tid * 8);
    const float4 a = s[0], c4 = s[1];
    *(float4*)&fl[0][tid * 8] = a;
    *(float4*)&fl[0][tid * 8 + 4] = c4;
    const float4* mb4 = (const float4*)(mask + (size_t)b * kT);
    for (int idx = tid; idx < kT / 4; idx += 192) ((float4*)ml)[idx] = mb4[idx];
    if (!bwd && h == 0) pbuf[0][i] = (i == kStart) ? 1.0f : 0.0f;
  }
  __syncthreads();
  float Lacc = 0.0f;
  float pown = bwd ? 1.0f : ((i == kStart) ? 1.0f : 0.0f);
  int cur = 0;
  float4 pfa, pfb;
  for (int tc = 0; tc < 32; ++tc) {
    const int fbuf = tc & 1;
    if (tc < 31) {
      const float4* s = (const float4*)(Fb + (size_t)(gb0 + (tc + 1) * gstep) * kS + tid * 8);
      pfa = s[0]; pfb = s[1];
    }
#pragma unroll
    for (int tt = 0; tt < 16; ++tt) {
      const int tl = tc * 16 + tt;
      const int t = bwd ? (kT - 1 - tl) : tl;
      const float f = fl[fbuf][(bwd ? (15 - tt) : tt) * kS + i];
      const float mkv = ml[t];
      if (!bwd) {
        const float* pc = &pbuf[cur][h * 48];
        float4 pv[12];
#pragma unroll
        for (int k = 0; k < 12; ++k) pv[k] = ((const float4*)pc)[k];
        float a0 = 0.f, a1 = 0.f, a2 = 0.f, a3 = 0.f;
#pragma unroll
        for (int k = 0; k < 12; ++k) {
          a0 = fmaf(mwv[4 * k + 0], pv[k].x, a0); a1 = fmaf(mwv[4 * k + 1], pv[k].y, a1);
          a2 = fmaf(mwv[4 * k + 2], pv[k].z, a2); a3 = fmaf(mwv[4 * k + 3], pv[k].w, a3);
        }
        float acc = (a0 + a1) + (a2 + a3);
        acc += __shfl_xor(acc, 1, 64);
        float pnew = (mkv > 0.f) ? acc * __expf(f - kCF) : pown;
        if (((tt + 1) & 7) == 0) renorm96(pv, pnew, Lacc);
        if (tt == 15 && tc < 31) {
          *(float4*)&fl[fbuf ^ 1][tid * 8] = pfa;
          *(float4*)&fl[fbuf ^ 1][tid * 8 + 4] = pfb;
        }
        if (h == 0) pbuf[cur ^ 1][i] = pnew;
        __syncthreads();
        pown = pnew;
      } else {
        const float uu = pown * __expf(f - kCF);
        if (h == 0) pbuf[cur ^ 1][i] = uu;
        if (tt == 15 && tc < 31) {
          *(float4*)&fl[fbuf ^ 1][tid * 8] = pfa;
          *(float4*)&fl[fbuf ^ 1][tid * 8 + 4] = pfb;
        }
        __syncthreads();
        const float* pc = &pbuf[cur ^ 1][h * 48];
        float4 pv[12];
#pragma unroll
        for (int k = 0; k < 12; ++k) pv[k] = ((const float4*)pc)[k];
        float a0 = 0.f, a1 = 0.f, a2 = 0.f, a3 = 0.f;
#pragma unroll
        for (int k = 0; k < 12; ++k) {
          a0 = fmaf(mwv[4 * k + 0], pv[k].x, a0); a1 = fmaf(mwv[4 * k + 1], pv[k].y, a1);
          a2 = fmaf(mwv[4 * k + 2], pv[k].z, a2); a3 = fmaf(mwv[4 * k + 3], pv[k].w, a3);
        }
        float acc = (a0 + a1) + (a2 + a3);
        acc += __shfl_xor(acc, 1, 64);
        float pnew = (mkv > 0.f) ? acc : pown;
        if (((tt + 1) & 7) == 0) renorm96(pv, pnew, Lacc);
        pown = pnew;
      }
      cur ^= 1;
    }
  }
  if (h == 0) ws[(bwd ? FB_WB : FB_PF) + b * kS + i] = pown;
  if (tid == 0) ws[(bwd ? FB_LB : FB_LF) + b] = Lacc;
}

__global__ __launch_bounds__(256) void fb_finalize(
    const float* __restrict__ F, const int* __restrict__ states,
    const float* __restrict__ mask, const float* __restrict__ trans,
    const float* __restrict__ ws, float* __restrict__ out) {
  const int b = blockIdx.x;
  const int tid = threadIdx.x;
  const int* st = states + b * kT;
  const float* Fb = F + (size_t)b * kT * kS;
  const float* mb = mask + b * kT;
  float acc = 0.f;
  for (int t = tid; t < kT; t += 256) {
    const int cu = st[t];
    const int pr = (t > 0) ? st[t - 1] : kStart;
    acc += (Fb[(size_t)t * kS + cu] + trans[cu * kS + pr]) * mb[t];
  }
  __shared__ float red[256];
  red[tid] = acc;
  __syncthreads();
  if (tid < 128) red[tid] += red[tid + 128];
  __syncthreads();
  float numv = 0.f;
  if (tid < 64) {
    float v = red[tid] + red[tid + 64];
#pragma unroll
    for (int off = 32; off > 0; off >>= 1) v += __shfl_xor(v, off, 64);
    numv = v;
  }
  __syncthreads();
  float dv = 0.f;
  if (tid < kS) dv = ws[FB_PF + b * kS + tid] * ws[FB_WB + b * kS + tid];
  red[tid] = dv;
  __syncthreads();
  if (tid < 128) red[tid] += red[tid + 128];
  __syncthreads();
  if (tid < 64) {
    float v = red[tid] + red[tid + 64];
#pragma unroll
    for (int off = 32; off > 0; off >>= 1) v += __shfl_xor(v, off, 64);
    if (tid == 0) out[b] = (ws[FB_LF + b] + ws[FB_LB + b] + logf(v)) - numv;
  }
}

}  // namespace

extern "C" void kernel_launch(void* const* d_in, const int* in_sizes, int n_in,
                              void* d_out, int out_size, void* d_ws, size_t ws_size,
                              hipStream_t stream) {
  const float* F      = (const float*)d_in[0];
  const int*   states = (const int*)d_in[1];
  const float* mask   = (const float*)d_in[2];
  const float* trans  = (const float*)d_in[3];
  float* out = (float*)d_out;
  if (ws_size >= kNeedBytes) {
    hipLaunchKernelGGL(crf_prep, dim3(kNSlots + kB), dim3(256), 0, stream,
                       F, states, mask, trans, (u32*)d_ws, (float*)d_ws);
    hipLaunchKernelGGL(crf_chains4, dim3(kNT / 4), dim3(512), 0, stream,
                       (const u32*)d_ws, trans, (float*)d_ws);
    hipLaunchKernelGGL(crf_fin, dim3(kB), dim3(64), 0, stream,
                       (const float*)d_ws, out);
  } else {
    float* ws = (float*)d_ws;
    hipLaunchKernelGGL(fb_halves, dim3(2 * kB), dim3(192), 0, stream, F, mask, trans, ws);
    hipLaunchKernelGGL(fb_finalize, dim3(kB), dim3(256), 0, stream,
                       F, states, mask, trans, ws, out);
  }
}

// Round 10
// 304.367 us; speedup vs baseline: 1.4705x; 1.4232x over previous
//
#include <hip/hip_runtime.h>

namespace {
constexpr int kB = 256, kT = 1024, kS = 96, kStart = 1;
constexpr float kCF = 3.5f;
constexpr float kLn2 = 0.69314718055994531f;

// ws float layout
constexpr int W_PF = 0;               // [kB][kS] fwd p after 512 steps
constexpr int W_LF = kB * kS;         // [kB]
constexpr int W_WB = W_LF + kB;       // [kB][kS] bwd w after 512 steps
constexpr int W_LB = W_WB + kB * kS;  // [kB]

// barrier-free renorm: max over the 96 values this thread+partner already
// read for the dot; exact power-of-2 scale; identical on all threads.
__device__ __forceinline__ void renorm96(const float4* pv, float& pnew, float& Lacc) {
  float4 m4 = pv[0];
#pragma unroll
  for (int k = 1; k < 12; ++k) {
    m4.x = fmaxf(m4.x, pv[k].x); m4.y = fmaxf(m4.y, pv[k].y);
    m4.z = fmaxf(m4.z, pv[k].z); m4.w = fmaxf(m4.w, pv[k].w);
  }
  float m = fmaxf(fmaxf(m4.x, m4.y), fmaxf(m4.z, m4.w));
  m = fmaxf(m, __shfl_xor(m, 1, 64));
  const int e = (__float_as_int(m) >> 23) & 0xFF;
  const float scale = __int_as_float((254 - e) << 23);   // 2^(127-e), exact
  Lacc += (float)(e - 127) * kLn2;
  pnew *= scale;
}

// Both half-chains of batch b in ONE 192-thread block (3 waves, 1/CU):
// fwd covers t=0..511 (p' = D M p), bwd covers t=1023..512 (w' = M^T D w).
// One __syncthreads per step; fwd-dot and bwd-u-write co-issue before it,
// bwd-dot and next fwd-dot co-issue after it (independent -> ILP).
__global__ __launch_bounds__(192) void crf_fused(
    const float* __restrict__ F, const float* __restrict__ mask,
    const float* __restrict__ trans, float* __restrict__ ws) {
  const int b = blockIdx.x;
  const int tid = threadIdx.x;
  const int h = tid & 1;      // half of the 96-dot
  const int i = tid >> 1;     // state row 0..95

  __shared__ __align__(16) float pF[2][kS];
  __shared__ __align__(16) float uB[2][kS];
  __shared__ __align__(16) float flF[2][16 * kS];   // fwd feature chunks (dbuf)
  __shared__ __align__(16) float flB[2][16 * kS];   // bwd feature chunks (dbuf)
  __shared__ __align__(16) float ml[kT];

  const float* Fb = F + (size_t)b * kT * kS;

  // matrix fragments in registers: fwd = M row-half, bwd = M^T row-half (M col)
  float mwF[48], mwB[48];
  {
    const float4* tp = (const float4*)(trans + i * kS + h * 48);
#pragma unroll
    for (int k = 0; k < 12; ++k) {
      const float4 tv = tp[k];
      mwF[4 * k + 0] = __expf(tv.x - kCF); mwF[4 * k + 1] = __expf(tv.y - kCF);
      mwF[4 * k + 2] = __expf(tv.z - kCF); mwF[4 * k + 3] = __expf(tv.w - kCF);
    }
  }
#pragma unroll
  for (int k = 0; k < 48; ++k)
    mwB[k] = __expf(trans[(h * 48 + k) * kS + i] - kCF);

  {  // stage chunk 0 for both directions + full mask row + init pF
    const float4* sF = (const float4*)(Fb + tid * 8);
    *(float4*)&flF[0][tid * 8] = sF[0];
    *(float4*)&flF[0][tid * 8 + 4] = sF[1];
    const float4* sB = (const float4*)(Fb + (size_t)(kT - 16) * kS + tid * 8);
    *(float4*)&flB[0][tid * 8] = sB[0];
    *(float4*)&flB[0][tid * 8 + 4] = sB[1];
    const float4* mb4 = (const float4*)(mask + (size_t)b * kT);
    for (int idx = tid; idx < kT / 4; idx += 192) ((float4*)ml)[idx] = mb4[idx];
    if (h == 0) pF[0][i] = (i == kStart) ? 1.0f : 0.0f;
  }
  __syncthreads();

  float pregF = (i == kStart) ? 1.0f : 0.0f;  // own fwd alpha (exp space)
  float pregB = 1.0f;                          // own bwd w
  float LF = 0.f, LB = 0.f;
  int cur = 0;
  float4 pfF0, pfF1, pfB0, pfB1;

  for (int tc = 0; tc < 32; ++tc) {
    const int fbuf = tc & 1;
    if (tc < 31) {   // issue next chunks' loads early; written at tt==15
      const float4* sF = (const float4*)(Fb + (size_t)(tc + 1) * 16 * kS + tid * 8);
      pfF0 = sF[0]; pfF1 = sF[1];
      const float4* sB =
          (const float4*)(Fb + (size_t)(kT - 16 - (tc + 1) * 16) * kS + tid * 8);
      pfB0 = sB[0]; pfB1 = sB[1];
    }
#pragma unroll
    for (int tt = 0; tt < 16; ++tt) {
      const int k = tc * 16 + tt;
      const int tb = kT - 1 - k;
      const int nxt = cur ^ 1;

      // ---- bwd-pre: u = w * ef(tb), publish for post-barrier dot ----
      const float fB = flB[fbuf][(15 - tt) * kS + i];
      const float uu = pregB * __expf(fB - kCF);
      if (h == 0) uB[nxt][i] = uu;

      // ---- fwd dot over pF[cur] ----
      float4 pvF[12];
      {
        const float4* pc = (const float4*)&pF[cur][h * 48];
#pragma unroll
        for (int q = 0; q < 12; ++q) pvF[q] = pc[q];
      }
      float a0 = 0.f, a1 = 0.f, a2 = 0.f, a3 = 0.f;
#pragma unroll
      for (int q = 0; q < 12; ++q) {
        a0 = fmaf(mwF[4 * q + 0], pvF[q].x, a0);
        a1 = fmaf(mwF[4 * q + 1], pvF[q].y, a1);
        a2 = fmaf(mwF[4 * q + 2], pvF[q].z, a2);
        a3 = fmaf(mwF[4 * q + 3], pvF[q].w, a3);
      }
      float accF = (a0 + a1) + (a2 + a3);
      accF += __shfl_xor(accF, 1, 64);
      const float fF = flF[fbuf][tt * kS + i];
      float pnewF = (ml[k] > 0.f) ? accF * __expf(fF - kCF) : pregF;
      if ((k & 7) == 7) renorm96(pvF, pnewF, LF);

      if (tt == 15 && tc < 31) {   // write-late half of the chunk staging
        *(float4*)&flF[fbuf ^ 1][tid * 8] = pfF0;
        *(float4*)&flF[fbuf ^ 1][tid * 8 + 4] = pfF1;
        *(float4*)&flB[fbuf ^ 1][tid * 8] = pfB0;
        *(float4*)&flB[fbuf ^ 1][tid * 8 + 4] = pfB1;
      }
      if (h == 0) pF[nxt][i] = pnewF;
      pregF = pnewF;

      __syncthreads();

      // ---- bwd dot over uB[nxt] (co-issues with next iteration's fwd dot) ----
      float4 pvB[12];
      {
        const float4* pc = (const float4*)&uB[nxt][h * 48];
#pragma unroll
        for (int q = 0; q < 12; ++q) pvB[q] = pc[q];
      }
      float b0 = 0.f, b1 = 0.f, b2 = 0.f, b3 = 0.f;
#pragma unroll
      for (int q = 0; q < 12; ++q) {
        b0 = fmaf(mwB[4 * q + 0], pvB[q].x, b0);
        b1 = fmaf(mwB[4 * q + 1], pvB[q].y, b1);
        b2 = fmaf(mwB[4 * q + 2], pvB[q].z, b2);
        b3 = fmaf(mwB[4 * q + 3], pvB[q].w, b3);
      }
      float accB = (b0 + b1) + (b2 + b3);
      accB += __shfl_xor(accB, 1, 64);
      float pnewB = (ml[tb] > 0.f) ? accB : pregB;
      if ((k & 7) == 7) renorm96(pvB, pnewB, LB);
      pregB = pnewB;

      cur = nxt;
    }
  }

  if (h == 0) {
    ws[W_PF + b * kS + i] = pregF;
    ws[W_WB + b * kS + i] = pregB;
  }
  if (tid == 0) {
    ws[W_LF + b] = LF;
    ws[W_LB + b] = LB;
  }
}

// finalize: numerator + mask-sum (bias) + combine halves
__global__ __launch_bounds__(256) void crf_fin2(
    const float* __restrict__ F, const int* __restrict__ states,
    const float* __restrict__ mask, const float* __restrict__ trans,
    const float* __restrict__ ws, float* __restrict__ out) {
  const int b = blockIdx.x;
  const int tid = threadIdx.x;
  const int* st = states + b * kT;
  const float* Fb = F + (size_t)b * kT * kS;
  const float* mb = mask + b * kT;

  float acc = 0.f, msum = 0.f;
  for (int t = tid; t < kT; t += 256) {
    const int cu = st[t];
    const int pr = (t > 0) ? st[t - 1] : kStart;
    const float mk = mb[t];
    acc += (Fb[(size_t)t * kS + cu] + trans[cu * kS + pr]) * mk;
    msum += mk;
  }
  __shared__ float red[256];
  __shared__ float numv_sh, msum_sh;
  red[tid] = acc;
  __syncthreads();
  if (tid < 128) red[tid] += red[tid + 128];
  __syncthreads();
  if (tid < 64) {
    float v = red[tid] + red[tid + 64];
#pragma unroll
    for (int off = 32; off > 0; off >>= 1) v += __shfl_xor(v, off, 64);
    if (tid == 0) numv_sh = v;
  }
  __syncthreads();
  red[tid] = msum;
  __syncthreads();
  if (tid < 128) red[tid] += red[tid + 128];
  __syncthreads();
  if (tid < 64) {
    float v = red[tid] + red[tid + 64];
#pragma unroll
    for (int off = 32; off > 0; off >>= 1) v += __shfl_xor(v, off, 64);
    if (tid == 0) msum_sh = v;
  }
  __syncthreads();

  float dv = 0.f;
  if (tid < kS) dv = ws[W_PF + b * kS + tid] * ws[W_WB + b * kS + tid];
  red[tid] = dv;
  __syncthreads();
  if (tid < 128) red[tid] += red[tid + 128];
  __syncthreads();
  if (tid < 64) {
    float v = red[tid] + red[tid + 64];
#pragma unroll
    for (int off = 32; off > 0; off >>= 1) v += __shfl_xor(v, off, 64);
    if (tid == 0)
      out[b] = (ws[W_LF + b] + ws[W_LB + b] + logf(v) + 2.f * kCF * msum_sh) - numv_sh;
  }
}
}  // namespace

extern "C" void kernel_launch(void* const* d_in, const int* in_sizes, int n_in,
                              void* d_out, int out_size, void* d_ws, size_t ws_size,
                              hipStream_t stream) {
  const float* F      = (const float*)d_in[0];
  const int*   states = (const int*)d_in[1];
  const float* mask   = (const float*)d_in[2];
  const float* trans  = (const float*)d_in[3];
  float* out = (float*)d_out;
  float* ws  = (float*)d_ws;   // ~198 KB used
  hipLaunchKernelGGL(crf_fused, dim3(kB), dim3(192), 0, stream,
                     F, mask, trans, ws);
  hipLaunchKernelGGL(crf_fin2, dim3(kB), dim3(256), 0, stream,
                     F, states, mask, trans, ws, out);
}